// Round 4
// baseline (441.846 us; speedup 1.0000x reference)
//
#include <hip/hip_runtime.h>

#define B_TOT 4096
#define T_LEN 512
#define DIN   8
#define H_DIM 50
#define BPB   16     // batches per chain (one wave owns all 50 h-dims for 16 batches)

typedef __attribute__((ext_vector_type(8))) short  short8;   // 8 bf16 (4 VGPRs)
typedef __attribute__((ext_vector_type(4))) float  floatx4;  // MFMA acc

__device__ __forceinline__ ushort f2bf_rne(float f) {
  uint u = __float_as_uint(f);
  u += 0x7FFFu + ((u >> 16) & 1u);
  return (ushort)(u >> 16);
}
__device__ __forceinline__ ushort f2bf_trunc(float f) {
  return (ushort)(__float_as_uint(f) >> 16);
}
__device__ __forceinline__ float bf2f(ushort b) {
  return __uint_as_float(((uint)b) << 16);
}
// intra-wave LDS RAW fence: in-order DS pipe + retire wait; no s_barrier needed
#define WAIT() asm volatile("s_waitcnt lgkmcnt(0)" ::: "memory")

__device__ __forceinline__ void tanh_split(float v, ushort& h, ushort& l) {
  float e  = __expf(2.0f * v);
  float th = 1.0f - 2.0f * __builtin_amdgcn_rcpf(1.0f + e);
  uint  u  = __float_as_uint(th);
  h = (ushort)(u >> 16);
  float hf = __uint_as_float(u & 0xFFFF0000u);
  l = f2bf_trunc(th - hf);
}

// LDS: ushort lds[4*1152]; plane (q*2+part)*1152, q = dbuf 0/1, part 0=hi 1=lo
// plane layout [batch n=0..15][k=0..71]: k 0..49 = h, 50..57 = x_t,
// 58..63 = zero K-pad, 64..71 = bank pad. Row stride 72 shorts (144 B).
// B-operand frag (h): lane (kg,n) reads 8 consecutive k -> ds_read_b128.
// Epilogue (C rows = h-out k, cols = batch): 4 consecutive k -> ds_write_b64.
#define ROWS 72
#define REG  1152

__global__ __launch_bounds__(64) void rnn_1wave(
    const float* __restrict__ x, const float* __restrict__ W_ih,
    const float* __restrict__ W_hh, const float* __restrict__ b_ih,
    const float* __restrict__ b_hh, const float* __restrict__ fc_W,
    const float* __restrict__ fc_b, float* __restrict__ out)
{
  __shared__ __align__(16) ushort lds[4 * REG];

  const int lane = threadIdx.x;    // 0..63, one wave
  const int col  = lane & 15;      // batch col (C/D n) AND h-frag batch row
  const int kg   = lane >> 4;      // 0..3
  const int b0   = blockIdx.x * BPB;

  // ---- W as A-operand: A[m=lane&15][k=kg*8+j]; 4 tiles x 2 K-halves, hi/lo ----
  union U8 { ushort u[8]; short8 v; };
  short8 Wh[4][2], Wl[4][2];
#pragma unroll
  for (int t4 = 0; t4 < 4; ++t4) {
    const int iG = t4 * 16 + col;          // h-out index of this lane's A-row
#pragma unroll
    for (int kh = 0; kh < 2; ++kh) {
      U8 hi_u, lo_u;
#pragma unroll
      for (int j = 0; j < 8; ++j) {
        int k = kh * 32 + kg * 8 + j;      // input index (h | x | pad)
        float w = 0.f;
        if (iG < H_DIM) {
          if (k < H_DIM)            w = W_hh[iG * H_DIM + k];
          else if (k < H_DIM + DIN) w = W_ih[iG * DIN + (k - H_DIM)];
        }
        ushort h = f2bf_rne(w);
        hi_u.u[j] = h;
        lo_u.u[j] = f2bf_trunc(w - bf2f(h));
      }
      Wh[t4][kh] = hi_u.v;
      Wl[t4][kh] = lo_u.v;
    }
  }

  // bias per acc reg: D row m = kg*4+r -> h-out = t4*16 + kg*4 + r
  floatx4 bias[4];
#pragma unroll
  for (int t4 = 0; t4 < 4; ++t4)
#pragma unroll
    for (int r = 0; r < 4; ++r) {
      int iG = t4 * 16 + kg * 4 + r;
      bias[t4][r] = (iG < H_DIM) ? (b_ih[iG] + b_hh[iG]) : 0.f;
    }

  // ---- zero both buffers (h0 = 0, pads = 0) ----
  for (int z = lane; z < 2304; z += 64) ((uint*)lds)[z] = 0;
  WAIT();

  // ---- x streaming: lane (col, kg) owns dims 2kg, 2kg+1 -> one float2/step ----
  const float2* xp2 = (const float2*)(x + ((size_t)(b0 + col) * T_LEN) * DIN) + kg;
  {
    float2 x0 = xp2[0];
    ushort h0x = f2bf_trunc(x0.x), h0y = f2bf_trunc(x0.y);
    *(uint*)&lds[0 * REG + col * ROWS + H_DIM + 2 * kg] = (uint)h0x | ((uint)h0y << 16);
    uint lx = (uint)f2bf_trunc(x0.x - bf2f(h0x)) | ((uint)f2bf_trunc(x0.y - bf2f(h0y)) << 16);
    *(uint*)&lds[1 * REG + col * ROWS + H_DIM + 2 * kg] = lx;
  }
  float2 px1 = xp2[4], px2 = xp2[8], px3 = xp2[12];   // t=1,2,3 in flight
  int toff = 16;                                       // float2 index of t=4
  WAIT();

  const int rdoff = col * ROWS + kg * 8;   // B-frag read base (shorts)
  const int wroff = col * ROWS;            // epilogue write base (shorts)

  // ---- main recurrence: zero barriers, one lgkm fence per step ----
  auto step = [&](int pr, int qr) {        // pr/qr = plane-pair base (shorts)
    const ushort* rp = lds + pr + rdoff;
    short8 Bh0 = *(const short8*)(rp);
    short8 Bh1 = *(const short8*)(rp + 32);
    short8 Bl0 = *(const short8*)(rp + REG);
    short8 Bl1 = *(const short8*)(rp + REG + 32);

    floatx4 v[4];
#pragma unroll
    for (int t4 = 0; t4 < 4; ++t4) {
      floatx4 a = bias[t4];
      a = __builtin_amdgcn_mfma_f32_16x16x32_bf16(Wh[t4][0], Bh0, a, 0, 0, 0);
      a = __builtin_amdgcn_mfma_f32_16x16x32_bf16(Wh[t4][1], Bh1, a, 0, 0, 0);
      floatx4 b = {0.f, 0.f, 0.f, 0.f};
      b = __builtin_amdgcn_mfma_f32_16x16x32_bf16(Wl[t4][0], Bh0, b, 0, 0, 0);
      b = __builtin_amdgcn_mfma_f32_16x16x32_bf16(Wl[t4][1], Bh1, b, 0, 0, 0);
      floatx4 c = {0.f, 0.f, 0.f, 0.f};
      c = __builtin_amdgcn_mfma_f32_16x16x32_bf16(Wh[t4][0], Bl0, c, 0, 0, 0);
      c = __builtin_amdgcn_mfma_f32_16x16x32_bf16(Wh[t4][1], Bl1, c, 0, 0, 0);
#pragma unroll
      for (int r = 0; r < 4; ++r) v[t4][r] = a[r] + b[r] + c[r];
    }

    ushort* wp = lds + qr + wroff;
    // tiles 0..2: h-out k = t4*16 + kg*4 + (0..3), all real (<48)
#pragma unroll
    for (int t4 = 0; t4 < 3; ++t4) {
      ushort h0, h1, h2, h3, l0, l1, l2, l3;
      tanh_split(v[t4][0], h0, l0);
      tanh_split(v[t4][1], h1, l1);
      tanh_split(v[t4][2], h2, l2);
      tanh_split(v[t4][3], h3, l3);
      uint2 hv = { (uint)h0 | ((uint)h1 << 16), (uint)h2 | ((uint)h3 << 16) };
      uint2 lv = { (uint)l0 | ((uint)l1 << 16), (uint)l2 | ((uint)l3 << 16) };
      *(uint2*)(wp + t4 * 16 + kg * 4)       = hv;
      *(uint2*)(wp + REG + t4 * 16 + kg * 4) = lv;
    }
    // tile 3: only h48, h49 exist (kg==0, r=0,1); k=50+ is the x region
    if (kg == 0) {
      ushort h0, h1, l0, l1;
      tanh_split(v[3][0], h0, l0);
      tanh_split(v[3][1], h1, l1);
      *(uint*)(wp + 48)       = (uint)h0 | ((uint)h1 << 16);
      *(uint*)(wp + REG + 48) = (uint)l0 | ((uint)l1 << 16);
    }
    // x staging for next step + prefetch rotate
    {
      ushort hx = f2bf_trunc(px1.x), hy = f2bf_trunc(px1.y);
      *(uint*)(wp + H_DIM + 2 * kg) = (uint)hx | ((uint)hy << 16);
      uint lx = (uint)f2bf_trunc(px1.x - bf2f(hx)) | ((uint)f2bf_trunc(px1.y - bf2f(hy)) << 16);
      *(uint*)(wp + REG + H_DIM + 2 * kg) = lx;
      px1 = px2; px2 = px3;
      px3 = xp2[toff];
      toff += 4; if (toff > (T_LEN - 1) * 4) toff = (T_LEN - 1) * 4;
    }
    WAIT();
  };

  for (int t = 0; t < T_LEN; t += 2) {
    step(0, 2 * REG);   // buf0 -> buf1
    step(2 * REG, 0);   // buf1 -> buf0
  }
  // h_T in buf0 (hi plane 0, lo plane REG)

  // ---- fc readout: 4 lanes per batch ----
  {
    int m = lane >> 2, kq = lane & 3;
    float acc = 0.f;
    for (int k = kq; k < H_DIM; k += 4) {
      float hv = bf2f(lds[m * ROWS + k]) + bf2f(lds[REG + m * ROWS + k]);
      acc += hv * fc_W[k];
    }
    acc += __shfl_xor(acc, 1);
    acc += __shfl_xor(acc, 2);
    if (kq == 0) out[b0 + m] = acc + fc_b[0];
  }
}

extern "C" void kernel_launch(void* const* d_in, const int* in_sizes, int n_in,
                              void* d_out, int out_size, void* d_ws, size_t ws_size,
                              hipStream_t stream) {
  const float* x    = (const float*)d_in[0];
  const float* W_ih = (const float*)d_in[1];
  const float* W_hh = (const float*)d_in[2];
  const float* b_ih = (const float*)d_in[3];
  const float* b_hh = (const float*)d_in[4];
  const float* fc_W = (const float*)d_in[5];
  const float* fc_b = (const float*)d_in[6];
  rnn_1wave<<<dim3(B_TOT / BPB), dim3(64), 0, stream>>>(
      x, W_ih, W_hh, b_ih, b_hh, fc_W, fc_b, (float*)d_out);
}